// Round 1
// baseline (117.515 us; speedup 1.0000x reference)
//
#include <hip/hip_runtime.h>
#include <hip/hip_bf16.h>

#define NTOT 8192   // 2B
#define BB   4096   // B
#define DD   256    // D

typedef __attribute__((ext_vector_type(8))) short short8v;  // 8 bf16 = 4 VGPR
typedef __attribute__((ext_vector_type(4))) float f32x4;

// XOR swizzle for row-major [rows][256] bf16 tiles (row stride 512 B).
// Spreads the 16-row column-slice read across 8 distinct 16B slots (2-way max,
// which is free). Applied identically on write and read (both-sides rule).
__device__ __forceinline__ int swz(int off) { return off ^ (((off >> 9) & 7) << 4); }

__device__ __forceinline__ unsigned short f2bf(float f) {
    __hip_bfloat16 h = __float2bfloat16(f);
    union { __hip_bfloat16 h; unsigned short u; } cv;
    cv.h = h;
    return cv.u;
}

// One wave per pair r: normalize x1[r], x2[r]; emit bf16 z rows r and r+BB;
// fp32 selfdot (z.z) and posdot (z1.z2).
__global__ __launch_bounds__(256) void k_normalize(
    const float* __restrict__ x1, const float* __restrict__ x2,
    unsigned short* __restrict__ zbf,
    float* __restrict__ selfdot, float* __restrict__ posdot)
{
    const int lane = threadIdx.x & 63;
    const int pair = blockIdx.x * 4 + (threadIdx.x >> 6);

    const float4 a = *(const float4*)(x1 + (size_t)pair * DD + lane * 4);
    const float4 b = *(const float4*)(x2 + (size_t)pair * DD + lane * 4);

    float s1 = a.x * a.x + a.y * a.y + a.z * a.z + a.w * a.w;
    float s2 = b.x * b.x + b.y * b.y + b.z * b.z + b.w * b.w;
#pragma unroll
    for (int off = 1; off < 64; off <<= 1) {
        s1 += __shfl_xor(s1, off);
        s2 += __shfl_xor(s2, off);
    }
    const float inv1 = 1.0f / fmaxf(sqrtf(s1), 1e-12f);
    const float inv2 = 1.0f / fmaxf(sqrtf(s2), 1e-12f);

    const float4 z1 = make_float4(a.x * inv1, a.y * inv1, a.z * inv1, a.w * inv1);
    const float4 z2 = make_float4(b.x * inv2, b.y * inv2, b.z * inv2, b.w * inv2);

    float sd1 = z1.x * z1.x + z1.y * z1.y + z1.z * z1.z + z1.w * z1.w;
    float sd2 = z2.x * z2.x + z2.y * z2.y + z2.z * z2.z + z2.w * z2.w;
    float pd  = z1.x * z2.x + z1.y * z2.y + z1.z * z2.z + z1.w * z2.w;
#pragma unroll
    for (int off = 1; off < 64; off <<= 1) {
        sd1 += __shfl_xor(sd1, off);
        sd2 += __shfl_xor(sd2, off);
        pd  += __shfl_xor(pd, off);
    }

    ushort4 u1, u2;
    u1.x = f2bf(z1.x); u1.y = f2bf(z1.y); u1.z = f2bf(z1.z); u1.w = f2bf(z1.w);
    u2.x = f2bf(z2.x); u2.y = f2bf(z2.y); u2.z = f2bf(z2.z); u2.w = f2bf(z2.w);
    *(ushort4*)(zbf + (size_t)pair * DD + lane * 4) = u1;
    *(ushort4*)(zbf + (size_t)(pair + BB) * DD + lane * 4) = u2;

    if (lane == 0) {
        selfdot[pair] = sd1;
        selfdot[pair + BB] = sd2;
        posdot[pair] = pd;
        posdot[pair + BB] = pd;
    }
}

// Block = 256 threads (4 waves). Each wave owns 64 rows (A fully in registers:
// 4 row-tiles x 8 k-steps of short8). Block covers 256 rows. Columns split
// across gridDim.y = 16; per block: 16 tiles of 32 columns staged in LDS.
// Per k-step/wave: 2 ds_read_b128 (B frags) -> 8 MFMA. exp(2*sim) folded into
// per-lane row-sum registers; final cross-lane reduce writes S partials.
__global__ __launch_bounds__(256, 2) void k_simsum(
    const unsigned short* __restrict__ zbf, float* __restrict__ S_part)
{
    __shared__ unsigned short Bsh[32 * DD];  // 16 KB, swizzled

    const int tid  = threadIdx.x;
    const int lane = tid & 63;
    const int wave = tid >> 6;
    const int frow = lane & 15;         // row (A) / col (B) within 16-tile
    const int kgrp = (lane >> 4) * 8;   // k sub-offset (elements)
    const int row0 = blockIdx.x * 256 + wave * 64;
    const int colBase = blockIdx.y * 512;

    // A: 64 rows x 256 k in registers (128 VGPR)
    short8v Afrag[4][8];
#pragma unroll
    for (int rt = 0; rt < 4; ++rt) {
        const int row = row0 + rt * 16 + frow;
#pragma unroll
        for (int kk = 0; kk < 8; ++kk)
            Afrag[rt][kk] = *(const short8v*)(zbf + (size_t)row * DD + kk * 32 + kgrp);
    }

    float rs[4][4];
#pragma unroll
    for (int rt = 0; rt < 4; ++rt)
#pragma unroll
        for (int q = 0; q < 4; ++q) rs[rt][q] = 0.0f;

    for (int t = 0; t < 16; ++t) {
        __syncthreads();
        {
            const uint4* src = (const uint4*)(zbf + (size_t)(colBase + t * 32) * DD);
#pragma unroll
            for (int i = 0; i < 4; ++i) {
                const int q = tid + i * 256;
                *(uint4*)((char*)Bsh + swz(q * 16)) = src[q];
            }
        }
        __syncthreads();

        f32x4 acc[4][2];
#pragma unroll
        for (int rt = 0; rt < 4; ++rt) {
#pragma unroll
            for (int c = 0; c < 2; ++c) {
                acc[rt][c][0] = 0.0f; acc[rt][c][1] = 0.0f;
                acc[rt][c][2] = 0.0f; acc[rt][c][3] = 0.0f;
            }
        }

#pragma unroll
        for (int kk = 0; kk < 8; ++kk) {
            const int kbyte = (kk * 32 + kgrp) * 2;
            const short8v b0 = *(const short8v*)((const char*)Bsh + swz(frow * 512 + kbyte));
            const short8v b1 = *(const short8v*)((const char*)Bsh + swz((16 + frow) * 512 + kbyte));
#pragma unroll
            for (int rt = 0; rt < 4; ++rt) {
                acc[rt][0] = __builtin_amdgcn_mfma_f32_16x16x32_bf16(Afrag[rt][kk], b0, acc[rt][0], 0, 0, 0);
                acc[rt][1] = __builtin_amdgcn_mfma_f32_16x16x32_bf16(Afrag[rt][kk], b1, acc[rt][1], 0, 0, 0);
            }
        }

#pragma unroll
        for (int rt = 0; rt < 4; ++rt)
#pragma unroll
            for (int q = 0; q < 4; ++q)
                rs[rt][q] += __expf(2.0f * acc[rt][0][q]) + __expf(2.0f * acc[rt][1][q]);
    }

    // C layout: col = lane&15, row = (lane>>4)*4 + q. Reduce over the 16 cols.
#pragma unroll
    for (int rt = 0; rt < 4; ++rt) {
#pragma unroll
        for (int q = 0; q < 4; ++q) {
            float v = rs[rt][q];
            v += __shfl_xor(v, 1);
            v += __shfl_xor(v, 2);
            v += __shfl_xor(v, 4);
            v += __shfl_xor(v, 8);
            if (frow == 0) {
                const int row = row0 + rt * 16 + (lane >> 4) * 4 + q;
                S_part[blockIdx.y * NTOT + row] = v;
            }
        }
    }
}

// Combine 16 column-split partials, subtract fp32 diagonal, clamp, log,
// subtract numerator log (= 2*posdot), mean over 8192 rows.
__global__ __launch_bounds__(256) void k_final(
    const float* __restrict__ S_part, const float* __restrict__ selfdot,
    const float* __restrict__ posdot, float* __restrict__ out)
{
    __shared__ float red[4];
    const int tid = threadIdx.x;
    float acc = 0.0f;
    for (int i = tid; i < NTOT; i += 256) {
        float s = 0.0f;
#pragma unroll
        for (int sp = 0; sp < 16; ++sp) s += S_part[sp * NTOT + i];
        const float den = fmaxf(s - expf(2.0f * selfdot[i]), 1e-8f);
        acc += logf(den) - 2.0f * posdot[i];
    }
#pragma unroll
    for (int off = 1; off < 64; off <<= 1) acc += __shfl_xor(acc, off);
    if ((tid & 63) == 0) red[tid >> 6] = acc;
    __syncthreads();
    if (tid == 0) out[0] = (red[0] + red[1] + red[2] + red[3]) * (1.0f / (float)NTOT);
}

extern "C" void kernel_launch(void* const* d_in, const int* in_sizes, int n_in,
                              void* d_out, int out_size, void* d_ws, size_t ws_size,
                              hipStream_t stream) {
    const float* x1 = (const float*)d_in[0];
    const float* x2 = (const float*)d_in[1];
    float* out = (float*)d_out;

    char* ws = (char*)d_ws;
    unsigned short* zbf = (unsigned short*)ws;                       // 4 MB
    size_t off = (size_t)NTOT * DD * sizeof(unsigned short);
    float* S_part = (float*)(ws + off);                              // 16*8192*4 = 512 KB
    off += (size_t)16 * NTOT * sizeof(float);
    float* selfdot = (float*)(ws + off);                             // 32 KB
    off += (size_t)NTOT * sizeof(float);
    float* posdot = (float*)(ws + off);                              // 32 KB

    k_normalize<<<dim3(BB / 4), dim3(256), 0, stream>>>(x1, x2, zbf, selfdot, posdot);
    k_simsum<<<dim3(32, 16), dim3(256), 0, stream>>>(zbf, S_part);
    k_final<<<dim3(1), dim3(256), 0, stream>>>(S_part, selfdot, posdot, out);
}

// Round 3
// 110.017 us; speedup vs baseline: 1.0681x; 1.0681x over previous
//
#include <hip/hip_runtime.h>
#include <hip/hip_bf16.h>

#define NTOT 8192   // 2B
#define BB   4096   // B
#define DD   256    // D

typedef __attribute__((ext_vector_type(8))) short short8v;  // 8 bf16 = 4 VGPR
typedef __attribute__((ext_vector_type(4))) float f32x4;

__device__ __forceinline__ unsigned short f2bf(float f) {
    union { __hip_bfloat16 h; unsigned short u; } cv;
    cv.h = __float2bfloat16(f);
    return cv.u;
}

// One wave per pair r: normalize x1[r], x2[r]; emit bf16 z rows r and r+BB;
// fp32 selfdot (z.z) and posdot (z1.z2).
__global__ __launch_bounds__(256) void k_normalize(
    const float* __restrict__ x1, const float* __restrict__ x2,
    unsigned short* __restrict__ zbf,
    float* __restrict__ selfdot, float* __restrict__ posdot)
{
    const int lane = threadIdx.x & 63;
    const int pair = blockIdx.x * 4 + (threadIdx.x >> 6);

    const float4 a = *(const float4*)(x1 + (size_t)pair * DD + lane * 4);
    const float4 b = *(const float4*)(x2 + (size_t)pair * DD + lane * 4);

    float s1 = a.x * a.x + a.y * a.y + a.z * a.z + a.w * a.w;
    float s2 = b.x * b.x + b.y * b.y + b.z * b.z + b.w * b.w;
#pragma unroll
    for (int off = 1; off < 64; off <<= 1) {
        s1 += __shfl_xor(s1, off);
        s2 += __shfl_xor(s2, off);
    }
    const float inv1 = 1.0f / fmaxf(sqrtf(s1), 1e-12f);
    const float inv2 = 1.0f / fmaxf(sqrtf(s2), 1e-12f);

    const float4 z1 = make_float4(a.x * inv1, a.y * inv1, a.z * inv1, a.w * inv1);
    const float4 z2 = make_float4(b.x * inv2, b.y * inv2, b.z * inv2, b.w * inv2);

    float sd1 = z1.x * z1.x + z1.y * z1.y + z1.z * z1.z + z1.w * z1.w;
    float sd2 = z2.x * z2.x + z2.y * z2.y + z2.z * z2.z + z2.w * z2.w;
    float pd  = z1.x * z2.x + z1.y * z2.y + z1.z * z2.z + z1.w * z2.w;
#pragma unroll
    for (int off = 1; off < 64; off <<= 1) {
        sd1 += __shfl_xor(sd1, off);
        sd2 += __shfl_xor(sd2, off);
        pd  += __shfl_xor(pd, off);
    }

    ushort4 u1, u2;
    u1.x = f2bf(z1.x); u1.y = f2bf(z1.y); u1.z = f2bf(z1.z); u1.w = f2bf(z1.w);
    u2.x = f2bf(z2.x); u2.y = f2bf(z2.y); u2.z = f2bf(z2.z); u2.w = f2bf(z2.w);
    *(ushort4*)(zbf + (size_t)pair * DD + lane * 4) = u1;
    *(ushort4*)(zbf + (size_t)(pair + BB) * DD + lane * 4) = u2;

    if (lane == 0) {
        selfdot[pair] = sd1;
        selfdot[pair + BB] = sd2;
        posdot[pair] = pd;
        posdot[pair + BB] = pd;
    }
}

// Block = 256 threads (4 waves). Each wave owns 64 rows; A fully in registers
// (4 row-tiles x 8 k-steps of short8 = 128 VGPR). Columns: blockIdx.y stripe of
// 512 cols = 8 steps of 64 cols, double-buffered in LDS via global_load_lds
// (width 16) with pre-swizzled SOURCE addresses (linear LDS dest, G21 rule);
// the ds_read side applies the SAME involution: addr = linear ^ ((col&7)<<4),
// XOR applied AFTER the full linear sum (carry-free: all terms disjoint bits).
// Per step: 8 gload_lds (prefetch next) + 32 ds_read_b128 + 128 MFMA + 64 exp,
// ONE barrier. exp(sim/T) = exp2(sim * 2/ln2) folded into per-lane row sums.
__global__ __launch_bounds__(256, 2) void k_simsum(
    const unsigned short* __restrict__ zbf, float* __restrict__ S_part)
{
    __shared__ char Bsh[2][32768];   // 2 x (64 cols x 512 B), 64 KB

    const int tid  = threadIdx.x;
    const int lane = tid & 63;
    const int wave = tid >> 6;
    const int frow = lane & 15;
    const int row0 = blockIdx.x * 256 + wave * 64;
    const int colStart = blockIdx.y * 512;

    // ---- A: 64 rows x 256 k in registers ----
    short8v Afrag[4][8];
#pragma unroll
    for (int rt = 0; rt < 4; ++rt) {
        const int row = row0 + rt * 16 + frow;
        const unsigned short* ap = zbf + (size_t)row * DD + (lane >> 4) * 8;
#pragma unroll
        for (int kk = 0; kk < 8; ++kk)
            Afrag[rt][kk] = *(const short8v*)(ap + kk * 32);
    }

    // Staging: thread's fixed pre-swizzled source offset; LDS dest is linear.
    // LDS slot L = r*4096 + tid*16 -> source U = r*4096 + (tid>>5)*512
    //            + ((tid&31) ^ ((tid>>5)&7))*16   (same involution as read)
    const int jswz = (tid & 31) ^ ((tid >> 5) & 7);
    const char* gsrc0 = (const char*)zbf + (size_t)colStart * 512
                        + (tid >> 5) * 512 + jswz * 16;

    // ds_read: base0 bits {4-5, 9-12}; kk*64 bits {6-8}; c*8192 bits {13-14};
    // mask bits {4-6}. (base0 + kk*64) ^ mask then + c*8192 == linear ^ mask.
    const int base0 = frow * 512 + (lane >> 4) * 16;
    const int bmask = (frow & 7) << 4;

    float rs[4][4];
#pragma unroll
    for (int rt = 0; rt < 4; ++rt)
#pragma unroll
        for (int q = 0; q < 4; ++q) rs[rt][q] = 0.0f;

    // prologue: stage step 0 into buffer 0
#pragma unroll
    for (int r = 0; r < 8; ++r)
        __builtin_amdgcn_global_load_lds(
            (const __attribute__((address_space(1))) unsigned int*)(gsrc0 + r * 4096),
            (__attribute__((address_space(3))) unsigned int*)(&Bsh[0][0] + tid * 16 + r * 4096),
            16, 0, 0);
    __syncthreads();

    int cur = 0;
    for (int t = 0; t < 8; ++t) {
        if (t < 7) {
            const char* gs = gsrc0 + (size_t)(t + 1) * 32768;
            char* ld = &Bsh[cur ^ 1][0] + tid * 16;
#pragma unroll
            for (int r = 0; r < 8; ++r)
                __builtin_amdgcn_global_load_lds(
                    (const __attribute__((address_space(1))) unsigned int*)(gs + r * 4096),
                    (__attribute__((address_space(3))) unsigned int*)(ld + r * 4096),
                    16, 0, 0);
        }

        // two passes of 2 column-chunks each (keeps live acc at [4][2])
#pragma unroll
        for (int c2 = 0; c2 < 2; ++c2) {
            f32x4 acc[4][2];
#pragma unroll
            for (int rt = 0; rt < 4; ++rt)
#pragma unroll
                for (int c = 0; c < 2; ++c) {
                    acc[rt][c][0] = 0.0f; acc[rt][c][1] = 0.0f;
                    acc[rt][c][2] = 0.0f; acc[rt][c][3] = 0.0f;
                }

#pragma unroll
            for (int kk = 0; kk < 8; ++kk) {
                const char* bp = &Bsh[cur][0] + ((base0 + kk * 64) ^ bmask)
                                 + c2 * 16384;
                short8v b0 = *(const short8v*)(bp);
                short8v b1 = *(const short8v*)(bp + 8192);
#pragma unroll
                for (int rt = 0; rt < 4; ++rt) {
                    acc[rt][0] = __builtin_amdgcn_mfma_f32_16x16x32_bf16(
                        Afrag[rt][kk], b0, acc[rt][0], 0, 0, 0);
                    acc[rt][1] = __builtin_amdgcn_mfma_f32_16x16x32_bf16(
                        Afrag[rt][kk], b1, acc[rt][1], 0, 0, 0);
                }
            }

#pragma unroll
            for (int rt = 0; rt < 4; ++rt)
#pragma unroll
                for (int q = 0; q < 4; ++q)
                    rs[rt][q] += exp2f(acc[rt][0][q] * 2.8853900817779268f)
                               + exp2f(acc[rt][1][q] * 2.8853900817779268f);
        }

        __syncthreads();   // drains staged loads (vmcnt) + protects buffer reuse
        cur ^= 1;
    }

    // C layout: col = lane&15, row = (lane>>4)*4 + q. Reduce over the 16 cols.
#pragma unroll
    for (int rt = 0; rt < 4; ++rt) {
#pragma unroll
        for (int q = 0; q < 4; ++q) {
            float v = rs[rt][q];
            v += __shfl_xor(v, 1);
            v += __shfl_xor(v, 2);
            v += __shfl_xor(v, 4);
            v += __shfl_xor(v, 8);
            if (frow == 0) {
                const int row = row0 + rt * 16 + (lane >> 4) * 4 + q;
                S_part[blockIdx.y * NTOT + row] = v;
            }
        }
    }
}

__global__ void k_zero(float* out) { out[0] = 0.0f; }

// 32 blocks x 256 threads: each thread one row. Combine 16 partials, subtract
// fp32 diagonal, log, subtract numerator (= 2*posdot); block-reduce; atomicAdd.
__global__ __launch_bounds__(256) void k_final(
    const float* __restrict__ S_part, const float* __restrict__ selfdot,
    const float* __restrict__ posdot, float* __restrict__ out)
{
    __shared__ float red[4];
    const int tid = threadIdx.x;
    const int i = blockIdx.x * 256 + tid;
    float s = 0.0f;
#pragma unroll
    for (int sp = 0; sp < 16; ++sp) s += S_part[sp * NTOT + i];
    const float den = fmaxf(s - expf(2.0f * selfdot[i]), 1e-8f);
    float acc = logf(den) - 2.0f * posdot[i];
#pragma unroll
    for (int off = 1; off < 64; off <<= 1) acc += __shfl_xor(acc, off);
    if ((tid & 63) == 0) red[tid >> 6] = acc;
    __syncthreads();
    if (tid == 0)
        atomicAdd(out, (red[0] + red[1] + red[2] + red[3]) * (1.0f / (float)NTOT));
}

extern "C" void kernel_launch(void* const* d_in, const int* in_sizes, int n_in,
                              void* d_out, int out_size, void* d_ws, size_t ws_size,
                              hipStream_t stream) {
    const float* x1 = (const float*)d_in[0];
    const float* x2 = (const float*)d_in[1];
    float* out = (float*)d_out;

    char* ws = (char*)d_ws;
    unsigned short* zbf = (unsigned short*)ws;                       // 4 MB
    size_t off = (size_t)NTOT * DD * sizeof(unsigned short);
    float* S_part = (float*)(ws + off);                              // 512 KB
    off += (size_t)16 * NTOT * sizeof(float);
    float* selfdot = (float*)(ws + off);                             // 32 KB
    off += (size_t)NTOT * sizeof(float);
    float* posdot = (float*)(ws + off);                              // 32 KB

    k_normalize<<<dim3(BB / 4), dim3(256), 0, stream>>>(x1, x2, zbf, selfdot, posdot);
    k_simsum<<<dim3(32, 16), dim3(256), 0, stream>>>(zbf, S_part);
    k_zero<<<dim3(1), dim3(1), 0, stream>>>(out);
    k_final<<<dim3(32), dim3(256), 0, stream>>>(S_part, selfdot, posdot, out);
}

// Round 4
// 108.219 us; speedup vs baseline: 1.0859x; 1.0166x over previous
//
#include <hip/hip_runtime.h>
#include <hip/hip_bf16.h>

#define NTOT 8192   // 2B
#define BB   4096   // B
#define DD   256    // D

typedef __attribute__((ext_vector_type(8))) short short8v;  // 8 bf16 = 4 VGPR
typedef __attribute__((ext_vector_type(4))) float f32x4;

__device__ __forceinline__ unsigned short f2bf(float f) {
    union { __hip_bfloat16 h; unsigned short u; } cv;
    cv.h = __float2bfloat16(f);
    return cv.u;
}

// One wave per pair r: normalize x1[r], x2[r]; emit bf16 z rows r and r+BB;
// fp32 selfdot (z.z) and posdot (z1.z2). Block 0 also zeroes out[0] for the
// k_final atomicAdd (stream-ordered before k_final, safe).
__global__ __launch_bounds__(256) void k_normalize(
    const float* __restrict__ x1, const float* __restrict__ x2,
    unsigned short* __restrict__ zbf,
    float* __restrict__ selfdot, float* __restrict__ posdot,
    float* __restrict__ out)
{
    if (blockIdx.x == 0 && threadIdx.x == 0) out[0] = 0.0f;

    const int lane = threadIdx.x & 63;
    const int pair = blockIdx.x * 4 + (threadIdx.x >> 6);

    const float4 a = *(const float4*)(x1 + (size_t)pair * DD + lane * 4);
    const float4 b = *(const float4*)(x2 + (size_t)pair * DD + lane * 4);

    float s1 = a.x * a.x + a.y * a.y + a.z * a.z + a.w * a.w;
    float s2 = b.x * b.x + b.y * b.y + b.z * b.z + b.w * b.w;
#pragma unroll
    for (int off = 1; off < 64; off <<= 1) {
        s1 += __shfl_xor(s1, off);
        s2 += __shfl_xor(s2, off);
    }
    const float inv1 = 1.0f / fmaxf(sqrtf(s1), 1e-12f);
    const float inv2 = 1.0f / fmaxf(sqrtf(s2), 1e-12f);

    const float4 z1 = make_float4(a.x * inv1, a.y * inv1, a.z * inv1, a.w * inv1);
    const float4 z2 = make_float4(b.x * inv2, b.y * inv2, b.z * inv2, b.w * inv2);

    float sd1 = z1.x * z1.x + z1.y * z1.y + z1.z * z1.z + z1.w * z1.w;
    float sd2 = z2.x * z2.x + z2.y * z2.y + z2.z * z2.z + z2.w * z2.w;
    float pd  = z1.x * z2.x + z1.y * z2.y + z1.z * z2.z + z1.w * z2.w;
#pragma unroll
    for (int off = 1; off < 64; off <<= 1) {
        sd1 += __shfl_xor(sd1, off);
        sd2 += __shfl_xor(sd2, off);
        pd  += __shfl_xor(pd, off);
    }

    ushort4 u1, u2;
    u1.x = f2bf(z1.x); u1.y = f2bf(z1.y); u1.z = f2bf(z1.z); u1.w = f2bf(z1.w);
    u2.x = f2bf(z2.x); u2.y = f2bf(z2.y); u2.z = f2bf(z2.z); u2.w = f2bf(z2.w);
    *(ushort4*)(zbf + (size_t)pair * DD + lane * 4) = u1;
    *(ushort4*)(zbf + (size_t)(pair + BB) * DD + lane * 4) = u2;

    if (lane == 0) {
        selfdot[pair] = sd1;
        selfdot[pair + BB] = sd2;
        posdot[pair] = pd;
        posdot[pair + BB] = pd;
    }
}

// Block = 256 threads (4 waves). Each wave owns 64 rows; A fully in registers
// (4 row-tiles x 8 k-steps of short8 = 128 VGPR), pinned with an opaque asm
// keep-alive so the allocator cannot rematerialize the loads inside the loop
// (round-3 counters: VGPR_Count=128 => A was demoted, ~38us of L2-reload
// stalls). Columns: blockIdx.y stripe of 512 cols = 8 steps of 64 cols,
// double-buffered in LDS via global_load_lds width-16 with pre-swizzled
// SOURCE addresses (linear LDS dest, G21); ds_read applies the same
// involution: addr = linear ^ ((col&7)<<4). One barrier per step.
// exp(sim/T) = exp2(sim * 2/ln2) folded into per-lane row sums.
__global__ __launch_bounds__(256, 2) void k_simsum(
    const unsigned short* __restrict__ zbf, float* __restrict__ S_part)
{
    __shared__ char Bsh[2][32768];   // 2 x (64 cols x 512 B), 64 KB -> 2 blk/CU

    const int tid  = threadIdx.x;
    const int lane = tid & 63;
    const int wave = tid >> 6;
    const int frow = lane & 15;
    const int row0 = blockIdx.x * 256 + wave * 64;
    const int colStart = blockIdx.y * 512;

    // ---- A: 64 rows x 256 k in registers, pinned ----
    short8v Afrag[4][8];
#pragma unroll
    for (int rt = 0; rt < 4; ++rt) {
        const int row = row0 + rt * 16 + frow;
        const unsigned short* ap = zbf + (size_t)row * DD + (lane >> 4) * 8;
#pragma unroll
        for (int kk = 0; kk < 8; ++kk)
            Afrag[rt][kk] = *(const short8v*)(ap + kk * 32);
    }
#pragma unroll
    for (int rt = 0; rt < 4; ++rt)
#pragma unroll
        for (int kk = 0; kk < 8; ++kk)
            asm volatile("" : "+v"(Afrag[rt][kk]));   // opaque def: no remat

    // Staging: pre-swizzled source offset; LDS dest linear (G21 rule).
    const int jswz = (tid & 31) ^ ((tid >> 5) & 7);
    const char* gsrc0 = (const char*)zbf + (size_t)colStart * 512
                        + (tid >> 5) * 512 + jswz * 16;

    // ds_read: base0 bits {4-5,9-12}; kk*64 bits {6-8}; c2*16384 bits {14};
    // mask bits {4-6}; (base0+kk*64)^mask then +c2*16384 == linear^mask.
    const int base0 = frow * 512 + (lane >> 4) * 16;
    const int bmask = (frow & 7) << 4;

    float rs[4][4];
#pragma unroll
    for (int rt = 0; rt < 4; ++rt)
#pragma unroll
        for (int q = 0; q < 4; ++q) rs[rt][q] = 0.0f;

    // prologue: stage step 0 into buffer 0
#pragma unroll
    for (int r = 0; r < 8; ++r)
        __builtin_amdgcn_global_load_lds(
            (const __attribute__((address_space(1))) unsigned int*)(gsrc0 + r * 4096),
            (__attribute__((address_space(3))) unsigned int*)(&Bsh[0][0] + tid * 16 + r * 4096),
            16, 0, 0);
    __syncthreads();

    int cur = 0;
    for (int t = 0; t < 8; ++t) {
        if (t < 7) {
            const char* gs = gsrc0 + (size_t)(t + 1) * 32768;
            char* ld = &Bsh[cur ^ 1][0] + tid * 16;
#pragma unroll
            for (int r = 0; r < 8; ++r)
                __builtin_amdgcn_global_load_lds(
                    (const __attribute__((address_space(1))) unsigned int*)(gs + r * 4096),
                    (__attribute__((address_space(3))) unsigned int*)(ld + r * 4096),
                    16, 0, 0);
        }

        // two passes of 2 column-chunks each (keeps live acc at [4][2])
#pragma unroll
        for (int c2 = 0; c2 < 2; ++c2) {
            f32x4 acc[4][2];
#pragma unroll
            for (int rt = 0; rt < 4; ++rt)
#pragma unroll
                for (int c = 0; c < 2; ++c) {
                    acc[rt][c][0] = 0.0f; acc[rt][c][1] = 0.0f;
                    acc[rt][c][2] = 0.0f; acc[rt][c][3] = 0.0f;
                }

#pragma unroll
            for (int kk = 0; kk < 8; ++kk) {
                const char* bp = &Bsh[cur][0] + ((base0 + kk * 64) ^ bmask)
                                 + c2 * 16384;
                short8v b0 = *(const short8v*)(bp);
                short8v b1 = *(const short8v*)(bp + 8192);
#pragma unroll
                for (int rt = 0; rt < 4; ++rt) {
                    acc[rt][0] = __builtin_amdgcn_mfma_f32_16x16x32_bf16(
                        Afrag[rt][kk], b0, acc[rt][0], 0, 0, 0);
                    acc[rt][1] = __builtin_amdgcn_mfma_f32_16x16x32_bf16(
                        Afrag[rt][kk], b1, acc[rt][1], 0, 0, 0);
                }
            }

#pragma unroll
            for (int rt = 0; rt < 4; ++rt)
#pragma unroll
                for (int q = 0; q < 4; ++q)
                    rs[rt][q] += exp2f(acc[rt][0][q] * 2.8853900817779268f)
                               + exp2f(acc[rt][1][q] * 2.8853900817779268f);
        }

        __syncthreads();   // drains staged loads (vmcnt) + protects buffer reuse
        cur ^= 1;
    }

    // C layout: col = lane&15, row = (lane>>4)*4 + q. Reduce over the 16 cols.
#pragma unroll
    for (int rt = 0; rt < 4; ++rt) {
#pragma unroll
        for (int q = 0; q < 4; ++q) {
            float v = rs[rt][q];
            v += __shfl_xor(v, 1);
            v += __shfl_xor(v, 2);
            v += __shfl_xor(v, 4);
            v += __shfl_xor(v, 8);
            if (frow == 0) {
                const int row = row0 + rt * 16 + (lane >> 4) * 4 + q;
                S_part[blockIdx.y * NTOT + row] = v;
            }
        }
    }
}

// 32 blocks x 256 threads: each thread one row. Combine 16 partials, subtract
// fp32 diagonal, log, subtract numerator (= 2*posdot); block-reduce; atomicAdd.
__global__ __launch_bounds__(256) void k_final(
    const float* __restrict__ S_part, const float* __restrict__ selfdot,
    const float* __restrict__ posdot, float* __restrict__ out)
{
    __shared__ float red[4];
    const int tid = threadIdx.x;
    const int i = blockIdx.x * 256 + tid;
    float s = 0.0f;
#pragma unroll
    for (int sp = 0; sp < 16; ++sp) s += S_part[sp * NTOT + i];
    const float den = fmaxf(s - expf(2.0f * selfdot[i]), 1e-8f);
    float acc = logf(den) - 2.0f * posdot[i];
#pragma unroll
    for (int off = 1; off < 64; off <<= 1) acc += __shfl_xor(acc, off);
    if ((tid & 63) == 0) red[tid >> 6] = acc;
    __syncthreads();
    if (tid == 0)
        atomicAdd(out, (red[0] + red[1] + red[2] + red[3]) * (1.0f / (float)NTOT));
}

extern "C" void kernel_launch(void* const* d_in, const int* in_sizes, int n_in,
                              void* d_out, int out_size, void* d_ws, size_t ws_size,
                              hipStream_t stream) {
    const float* x1 = (const float*)d_in[0];
    const float* x2 = (const float*)d_in[1];
    float* out = (float*)d_out;

    char* ws = (char*)d_ws;
    unsigned short* zbf = (unsigned short*)ws;                       // 4 MB
    size_t off = (size_t)NTOT * DD * sizeof(unsigned short);
    float* S_part = (float*)(ws + off);                              // 512 KB
    off += (size_t)16 * NTOT * sizeof(float);
    float* selfdot = (float*)(ws + off);                             // 32 KB
    off += (size_t)NTOT * sizeof(float);
    float* posdot = (float*)(ws + off);                              // 32 KB

    k_normalize<<<dim3(BB / 4), dim3(256), 0, stream>>>(x1, x2, zbf, selfdot, posdot, out);
    k_simsum<<<dim3(32, 16), dim3(256), 0, stream>>>(zbf, S_part);
    k_final<<<dim3(32), dim3(256), 0, stream>>>(S_part, selfdot, posdot, out);
}